// Round 9
// baseline (15203.731 us; speedup 1.0000x reference)
//
#include <hip/hip_runtime.h>
#include <hip/hip_bf16.h>
#include <cstdint>
#include <cstddef>

// Problem constants
#define T_STEPS 8192
#define IN_DIM  1024
#define HID     1024
#define OUT_DIM 1024
#define G4      4096   // 4*HID

// Recurrence geometry: 256 blocks x 256 threads (4 waves), 1 block/CU.
// Each wave owns 1 hidden unit (4 gate rows). Weights: 16 f32x4 = 64 VGPRs
// per lane, loaded from global ONCE and pinned with an opaque asm barrier
// OUTSIDE the t-loop (R7/R8 re-read 64KB/step from LDS -- ~770cy of LDS pipe
// in the critical path; R4-R6's in-loop pin couldn't stop rematerialization,
// a pre-loop pin makes remat impossible -- only scratch spill remains, which
// is no worse than the status quo).
#define NBLK 256
#define TPB  256
#define WPB  4    // waves per block
#define UPB  4    // units per block (1 per wave)

typedef __attribute__((ext_vector_type(4))) float f32x4;

__device__ __forceinline__ float sigf(float x) {
  return 1.0f / (1.0f + __expf(-x));
}

// Halving reduce step: pair (lane, lane^mask); lane with bit==0 ends with
// row-a total partial, bit==1 with row-b.
__device__ __forceinline__ float halvestep(float a, float b, int mask, int lane) {
  float x = (lane & mask) ? a : b;     // what my partner needs
  float y = __shfl_xor(x, mask);
  return ((lane & mask) ? b : a) + y;
}

// ---------------------------------------------------------------------------
// GEMM: C[M,N] = A[M,K] @ B[N,K]^T + bias[N]  (64x64 tile, 256 thr, 4x4 micro)
// ---------------------------------------------------------------------------
__global__ __launch_bounds__(256) void gemm_nt(
    const float* __restrict__ A, int lda,
    const float* __restrict__ B, int ldb,
    const float* __restrict__ bias,
    float* __restrict__ C, int ldc,
    int K)
{
  __shared__ float As[16][72];
  __shared__ float Bs[16][72];

  const int tid = threadIdx.x;
  const int m0 = blockIdx.y * 64;
  const int n0 = blockIdx.x * 64;
  const int lr = tid >> 2;
  const int lk = (tid & 3) * 4;
  const int ty = tid >> 4;
  const int tx = tid & 15;

  float acc[4][4];
#pragma unroll
  for (int i = 0; i < 4; ++i)
#pragma unroll
    for (int j = 0; j < 4; ++j) acc[i][j] = 0.0f;

  const float* Ag = A + (size_t)(m0 + lr) * lda + lk;
  const float* Bg = B + (size_t)(n0 + lr) * ldb + lk;

  for (int kt = 0; kt < K; kt += 16) {
    float4 av = *(const float4*)(Ag + kt);
    float4 bv = *(const float4*)(Bg + kt);
    __syncthreads();
    As[lk + 0][lr] = av.x; As[lk + 1][lr] = av.y;
    As[lk + 2][lr] = av.z; As[lk + 3][lr] = av.w;
    Bs[lk + 0][lr] = bv.x; Bs[lk + 1][lr] = bv.y;
    Bs[lk + 2][lr] = bv.z; Bs[lk + 3][lr] = bv.w;
    __syncthreads();
#pragma unroll
    for (int k = 0; k < 16; ++k) {
      float4 a4 = *(const float4*)&As[k][ty * 4];
      float4 b4 = *(const float4*)&Bs[k][tx * 4];
      acc[0][0] = fmaf(a4.x, b4.x, acc[0][0]); acc[0][1] = fmaf(a4.x, b4.y, acc[0][1]);
      acc[0][2] = fmaf(a4.x, b4.z, acc[0][2]); acc[0][3] = fmaf(a4.x, b4.w, acc[0][3]);
      acc[1][0] = fmaf(a4.y, b4.x, acc[1][0]); acc[1][1] = fmaf(a4.y, b4.y, acc[1][1]);
      acc[1][2] = fmaf(a4.y, b4.z, acc[1][2]); acc[1][3] = fmaf(a4.y, b4.w, acc[1][3]);
      acc[2][0] = fmaf(a4.z, b4.x, acc[2][0]); acc[2][1] = fmaf(a4.z, b4.y, acc[2][1]);
      acc[2][2] = fmaf(a4.z, b4.z, acc[2][2]); acc[2][3] = fmaf(a4.z, b4.w, acc[2][3]);
      acc[3][0] = fmaf(a4.w, b4.x, acc[3][0]); acc[3][1] = fmaf(a4.w, b4.y, acc[3][1]);
      acc[3][2] = fmaf(a4.w, b4.z, acc[3][2]); acc[3][3] = fmaf(a4.w, b4.w, acc[3][3]);
    }
  }

  float4 b4 = *(const float4*)(bias + n0 + tx * 4);
#pragma unroll
  for (int i = 0; i < 4; ++i) {
    float4 o;
    o.x = acc[i][0] + b4.x; o.y = acc[i][1] + b4.y;
    o.z = acc[i][2] + b4.z; o.w = acc[i][3] + b4.w;
    *(float4*)(C + (size_t)(m0 + ty * 4 + i) * ldc + n0 + tx * 4) = o;
  }
}

// ---------------------------------------------------------------------------
// Persistent recurrence: tagged dataflow (no device barrier) + VGPR-resident
// weights (pinned pre-loop) + per-block LDS h staging + raw LDS-only barrier.
//
// h element layout: chunk j (=wave slot) covers h[256j .. 256j+255]; lane l
// owns elements 256j + 4l + 0..3 (contiguous per lane -> poll loads are 4
// consecutive u64/lane, deposit is one ds_write_b128, weights load coalesced).
//
// Step t per wave:
//   B) issue pre[t+1] prefetch (stays in flight across the raw barrier)
//   C) poll my chunk of slot t&1 for tag t (4 consecutive tagged u64/lane);
//      deposit one float4 into lh[t&1]
//   D) s_waitcnt lgkmcnt(0); s_barrier   (vmem NOT drained)
//   E) 3 ds_read_b128 (other chunks) + own chunk from regs, 64 FMAs vs
//      pinned weights, 7-stage reduce, activations, lane 0 publishes unit u
//      with tag t+1 (fire-and-forget).
// Skew safety: every block consumes the FULL h each step -> tag t+2 store
// implies all blocks passed poll t+1 -> depth-2 slots never skip a tag.
// LDS parity buffers are race-free across the per-step barrier (deposit at
// t+2 is program-ordered after barrier t+1, which is after all reads at t).
// ---------------------------------------------------------------------------
__global__ __launch_bounds__(TPB, 1) void lstm_rec(
    const float* __restrict__ Ww,                 // [4096, 2048]
    const float* __restrict__ pre,                // [T, 4096]
    unsigned long long* __restrict__ hbuf,        // [2][1024] tagged
    float* __restrict__ hall)                     // [T, 1024]
{
  __shared__ float lh[2][HID];      // 8 KB: staged h, double-buffered

  const int tid = threadIdx.x;
  const int lane = tid & 63;
  const int wslot = tid >> 6;                 // 0..3 = unit-in-block, chunk id
  const int u = blockIdx.x * UPB + wslot;     // this wave's hidden unit

  // Per-lane gate identity (replicated x16 across the wave)
  const int g = lane & 3;            // 0:i 1:f 2:g 3:o
  const size_t preoff = (size_t)g * HID + u;

  // One-time weight load, coalesced: row r_g = g*HID+u (h-part), chunk j,
  // elements 4*lane..4*lane+3. 16 f32x4 = 64 VGPRs.
  f32x4 W00, W01, W02, W03, W10, W11, W12, W13,
        W20, W21, W22, W23, W30, W31, W32, W33;
  {
    const float* base = Ww + IN_DIM + 4 * lane;
#define LOADW(gg, jj) (*(const f32x4*)(base + (size_t)((gg) * HID + u) * (IN_DIM + HID) + (jj) * 256))
    W00 = LOADW(0, 0); W01 = LOADW(0, 1); W02 = LOADW(0, 2); W03 = LOADW(0, 3);
    W10 = LOADW(1, 0); W11 = LOADW(1, 1); W12 = LOADW(1, 2); W13 = LOADW(1, 3);
    W20 = LOADW(2, 0); W21 = LOADW(2, 1); W22 = LOADW(2, 2); W23 = LOADW(2, 3);
    W30 = LOADW(3, 0); W31 = LOADW(3, 1); W32 = LOADW(3, 2); W33 = LOADW(3, 3);
#undef LOADW
  }
  // Opaque pin OUTSIDE the loop: these become asm outputs -- the compiler
  // cannot rematerialize them by reloading; only scratch spill remains.
  asm volatile("" : "+v"(W00), "+v"(W01), "+v"(W02), "+v"(W03),
                    "+v"(W10), "+v"(W11), "+v"(W12), "+v"(W13),
                    "+v"(W20), "+v"(W21), "+v"(W22), "+v"(W23),
                    "+v"(W30), "+v"(W31), "+v"(W32), "+v"(W33));

  float c = 0.0f;
  float pv = pre[preoff];            // pre-gate for step 0 (pipelined)

  for (int t = 0; t < T_STEPS; ++t) {
    // B) next step's pre load -- full-step latency cover (never drained)
    const int tn = (t + 1 < T_STEPS) ? (t + 1) : t;
    const float pv_next = pre[(size_t)tn * G4 + preoff];

    // C) Poll my chunk of h_{t-1}: 4 consecutive tagged u64 loads/lane
    const unsigned long long* hs =
        hbuf + (size_t)(t & 1) * HID + wslot * 256 + 4 * lane;
    const unsigned want = (unsigned)t;
    unsigned long long p0, p1, p2, p3;
    for (;;) {
      p0 = __hip_atomic_load(hs + 0, __ATOMIC_RELAXED, __HIP_MEMORY_SCOPE_AGENT);
      p1 = __hip_atomic_load(hs + 1, __ATOMIC_RELAXED, __HIP_MEMORY_SCOPE_AGENT);
      p2 = __hip_atomic_load(hs + 2, __ATOMIC_RELAXED, __HIP_MEMORY_SCOPE_AGENT);
      p3 = __hip_atomic_load(hs + 3, __ATOMIC_RELAXED, __HIP_MEMORY_SCOPE_AGENT);
      bool ok = ((unsigned)p0 == want) & ((unsigned)p1 == want) &
                ((unsigned)p2 == want) & ((unsigned)p3 == want);
      if (__all((int)ok)) break;
    }
    f32x4 own;
    own.x = __uint_as_float((unsigned)(p0 >> 32));
    own.y = __uint_as_float((unsigned)(p1 >> 32));
    own.z = __uint_as_float((unsigned)(p2 >> 32));
    own.w = __uint_as_float((unsigned)(p3 >> 32));
    *(f32x4*)&lh[t & 1][wslot * 256 + 4 * lane] = own;   // one ds_write_b128

    // D) raw barrier: drain LDS ops only; global loads/stores stay in flight
    asm volatile("s_waitcnt lgkmcnt(0)\n\ts_barrier" ::: "memory");

    // E) other 3 chunks from LDS (3 x ds_read_b128), own chunk from regs
    const f32x4* lhp = (const f32x4*)&lh[t & 1][0];
    f32x4 hv0 = (wslot == 0) ? own : lhp[0 * 64 + lane];
    f32x4 hv1 = (wslot == 1) ? own : lhp[1 * 64 + lane];
    f32x4 hv2 = (wslot == 2) ? own : lhp[2 * 64 + lane];
    f32x4 hv3 = (wslot == 3) ? own : lhp[3 * 64 + lane];

    // 4 gate-row dots vs pinned weights (64 FMA/lane)
    float a0, a1, a2, a3;
    {
      float a;
      a = 0.0f;
      a = fmaf(W00.x, hv0.x, a); a = fmaf(W00.y, hv0.y, a); a = fmaf(W00.z, hv0.z, a); a = fmaf(W00.w, hv0.w, a);
      a = fmaf(W01.x, hv1.x, a); a = fmaf(W01.y, hv1.y, a); a = fmaf(W01.z, hv1.z, a); a = fmaf(W01.w, hv1.w, a);
      a = fmaf(W02.x, hv2.x, a); a = fmaf(W02.y, hv2.y, a); a = fmaf(W02.z, hv2.z, a); a = fmaf(W02.w, hv2.w, a);
      a = fmaf(W03.x, hv3.x, a); a = fmaf(W03.y, hv3.y, a); a = fmaf(W03.z, hv3.z, a); a = fmaf(W03.w, hv3.w, a);
      a0 = a;
      a = 0.0f;
      a = fmaf(W10.x, hv0.x, a); a = fmaf(W10.y, hv0.y, a); a = fmaf(W10.z, hv0.z, a); a = fmaf(W10.w, hv0.w, a);
      a = fmaf(W11.x, hv1.x, a); a = fmaf(W11.y, hv1.y, a); a = fmaf(W11.z, hv1.z, a); a = fmaf(W11.w, hv1.w, a);
      a = fmaf(W12.x, hv2.x, a); a = fmaf(W12.y, hv2.y, a); a = fmaf(W12.z, hv2.z, a); a = fmaf(W12.w, hv2.w, a);
      a = fmaf(W13.x, hv3.x, a); a = fmaf(W13.y, hv3.y, a); a = fmaf(W13.z, hv3.z, a); a = fmaf(W13.w, hv3.w, a);
      a1 = a;
      a = 0.0f;
      a = fmaf(W20.x, hv0.x, a); a = fmaf(W20.y, hv0.y, a); a = fmaf(W20.z, hv0.z, a); a = fmaf(W20.w, hv0.w, a);
      a = fmaf(W21.x, hv1.x, a); a = fmaf(W21.y, hv1.y, a); a = fmaf(W21.z, hv1.z, a); a = fmaf(W21.w, hv1.w, a);
      a = fmaf(W22.x, hv2.x, a); a = fmaf(W22.y, hv2.y, a); a = fmaf(W22.z, hv2.z, a); a = fmaf(W22.w, hv2.w, a);
      a = fmaf(W23.x, hv3.x, a); a = fmaf(W23.y, hv3.y, a); a = fmaf(W23.z, hv3.z, a); a = fmaf(W23.w, hv3.w, a);
      a2 = a;
      a = 0.0f;
      a = fmaf(W30.x, hv0.x, a); a = fmaf(W30.y, hv0.y, a); a = fmaf(W30.z, hv0.z, a); a = fmaf(W30.w, hv0.w, a);
      a = fmaf(W31.x, hv1.x, a); a = fmaf(W31.y, hv1.y, a); a = fmaf(W31.z, hv1.z, a); a = fmaf(W31.w, hv1.w, a);
      a = fmaf(W32.x, hv2.x, a); a = fmaf(W32.y, hv2.y, a); a = fmaf(W32.z, hv2.z, a); a = fmaf(W32.w, hv2.w, a);
      a = fmaf(W33.x, hv3.x, a); a = fmaf(W33.y, hv3.y, a); a = fmaf(W33.z, hv3.z, a); a = fmaf(W33.w, hv3.w, a);
      a3 = a;
    }

    // Halving reduce: 3 shuffles land gate (lane&3) in lane; 4 butterflies
    float r0 = halvestep(a0, a1, 1, lane);
    float r1 = halvestep(a2, a3, 1, lane);
    float s  = halvestep(r0, r1, 2, lane);
    s += __shfl_xor(s, 4); s += __shfl_xor(s, 8);
    s += __shfl_xor(s, 16); s += __shfl_xor(s, 32);
    // lane l holds the full pre-activation sum for gate l&3

    const float gv = s + pv;
    // sigmoid for i,f,o; tanh for g via 2*sig(2x)-1
    const bool isg = (g == 2);
    const float sg = sigf(isg ? 2.0f * gv : gv);
    const float act = isg ? fmaf(2.0f, sg, -1.0f) : sg;

    // gather my quad's four gate activations
    const int base = lane & ~3;
    const float si = __shfl(act, base);
    const float sf = __shfl(act, base | 1);
    const float tg = __shfl(act, base | 2);
    const float so = __shfl(act, base | 3);

    c = fmaf(sf, c, si * tg);
    const float s2 = sigf(2.0f * c);
    const float h = so * fmaf(2.0f, s2, -1.0f);   // so * tanh(c)

    if (lane == 0) {
      unsigned long long pk =
          ((unsigned long long)__float_as_uint(h) << 32) | (unsigned)(t + 1);
      __hip_atomic_store(hbuf + (size_t)((t + 1) & 1) * HID + u, pk,
                         __ATOMIC_RELAXED, __HIP_MEMORY_SCOPE_AGENT);
      hall[(size_t)t * HID + u] = h;
    }

    pv = pv_next;
  }
}

// ---------------------------------------------------------------------------
// Workspace layout (bytes):
//   [0, 16K)              : hbuf[2][1024] tagged u64  (memset 0: tag0/h=0)
//   [16K, 16K+33.5MB)     : hall[T][1024]
//   [16K+33.5MB, +134MB)  : pre[T][4096]
// ---------------------------------------------------------------------------
extern "C" void kernel_launch(void* const* d_in, const int* in_sizes, int n_in,
                              void* d_out, int out_size, void* d_ws, size_t ws_size,
                              hipStream_t stream) {
  (void)in_sizes; (void)n_in; (void)out_size; (void)ws_size;

  const float* x     = (const float*)d_in[0];  // [T,1,IN]
  const float* W_w   = (const float*)d_in[1];  // [4096, 2048]
  const float* W_b   = (const float*)d_in[2];  // [4096]
  const float* out_w = (const float*)d_in[3];  // [1024, 1024]
  const float* out_b = (const float*)d_in[4];  // [1024]
  float* out = (float*)d_out;                  // [T,1,1024]

  char* ws = (char*)d_ws;
  unsigned long long* hbuf = (unsigned long long*)ws;
  float* hall = (float*)(ws + 16384);
  float* pre  = (float*)(ws + 16384 + (size_t)T_STEPS * HID * 4);

  hipMemsetAsync(ws, 0, 16384, stream);

  // pre = x @ Wx^T + W_b   (Wx = W_w[:, :1024], row stride 2048)
  gemm_nt<<<dim3(G4 / 64, T_STEPS / 64), 256, 0, stream>>>(
      x, IN_DIM, W_w, IN_DIM + HID, W_b, pre, G4, IN_DIM);

  // sequential recurrence: 256 blocks (1/CU), VGPR-resident weights
  lstm_rec<<<NBLK, TPB, 0, stream>>>(W_w, pre, hbuf, hall);

  // y = hall @ out_w^T + out_b
  gemm_nt<<<dim3(OUT_DIM / 64, T_STEPS / 64), 256, 0, stream>>>(
      hall, HID, out_w, OUT_DIM, out_b, out, OUT_DIM, HID);
}

// Round 10
// 15170.691 us; speedup vs baseline: 1.0022x; 1.0022x over previous
//
#include <hip/hip_runtime.h>
#include <hip/hip_bf16.h>
#include <cstdint>
#include <cstddef>

// Problem constants
#define T_STEPS 8192
#define IN_DIM  1024
#define HID     1024
#define OUT_DIM 1024
#define G4      4096   // 4*HID

// Recurrence geometry: 256 blocks x 256 threads (4 waves), 1 block/CU.
// Each wave owns 1 hidden unit (4 gate rows); weights = 16 f32x4 = 64 VGPRs
// per lane, loaded once pre-loop. R4-R9 lesson: the register allocator
// budgets ~84 VGPRs (a ~6-waves/EU occupancy heuristic) regardless of
// __launch_bounds__, spilling/rematerializing the weights every step --
// amdgpu_waves_per_eu(1,1) pins the budget at 512 VGPRs (truthful: we run
// 4 waves/CU = 1 wave/EU), removing the spill motive entirely.
#define NBLK 256
#define TPB  256
#define WPB  4    // waves per block
#define UPB  4    // units per block (1 per wave)

typedef __attribute__((ext_vector_type(4))) float f32x4;

__device__ __forceinline__ float sigf(float x) {
  return 1.0f / (1.0f + __expf(-x));
}

// Halving reduce step: pair (lane, lane^mask); lane with bit==0 ends with
// row-a total partial, bit==1 with row-b.
__device__ __forceinline__ float halvestep(float a, float b, int mask, int lane) {
  float x = (lane & mask) ? a : b;     // what my partner needs
  float y = __shfl_xor(x, mask);
  return ((lane & mask) ? b : a) + y;
}

// ---------------------------------------------------------------------------
// GEMM: C[M,N] = A[M,K] @ B[N,K]^T + bias[N]  (64x64 tile, 256 thr, 4x4 micro)
// ---------------------------------------------------------------------------
__global__ __launch_bounds__(256) void gemm_nt(
    const float* __restrict__ A, int lda,
    const float* __restrict__ B, int ldb,
    const float* __restrict__ bias,
    float* __restrict__ C, int ldc,
    int K)
{
  __shared__ float As[16][72];
  __shared__ float Bs[16][72];

  const int tid = threadIdx.x;
  const int m0 = blockIdx.y * 64;
  const int n0 = blockIdx.x * 64;
  const int lr = tid >> 2;
  const int lk = (tid & 3) * 4;
  const int ty = tid >> 4;
  const int tx = tid & 15;

  float acc[4][4];
#pragma unroll
  for (int i = 0; i < 4; ++i)
#pragma unroll
    for (int j = 0; j < 4; ++j) acc[i][j] = 0.0f;

  const float* Ag = A + (size_t)(m0 + lr) * lda + lk;
  const float* Bg = B + (size_t)(n0 + lr) * ldb + lk;

  for (int kt = 0; kt < K; kt += 16) {
    float4 av = *(const float4*)(Ag + kt);
    float4 bv = *(const float4*)(Bg + kt);
    __syncthreads();
    As[lk + 0][lr] = av.x; As[lk + 1][lr] = av.y;
    As[lk + 2][lr] = av.z; As[lk + 3][lr] = av.w;
    Bs[lk + 0][lr] = bv.x; Bs[lk + 1][lr] = bv.y;
    Bs[lk + 2][lr] = bv.z; Bs[lk + 3][lr] = bv.w;
    __syncthreads();
#pragma unroll
    for (int k = 0; k < 16; ++k) {
      float4 a4 = *(const float4*)&As[k][ty * 4];
      float4 b4 = *(const float4*)&Bs[k][tx * 4];
      acc[0][0] = fmaf(a4.x, b4.x, acc[0][0]); acc[0][1] = fmaf(a4.x, b4.y, acc[0][1]);
      acc[0][2] = fmaf(a4.x, b4.z, acc[0][2]); acc[0][3] = fmaf(a4.x, b4.w, acc[0][3]);
      acc[1][0] = fmaf(a4.y, b4.x, acc[1][0]); acc[1][1] = fmaf(a4.y, b4.y, acc[1][1]);
      acc[1][2] = fmaf(a4.y, b4.z, acc[1][2]); acc[1][3] = fmaf(a4.y, b4.w, acc[1][3]);
      acc[2][0] = fmaf(a4.z, b4.x, acc[2][0]); acc[2][1] = fmaf(a4.z, b4.y, acc[2][1]);
      acc[2][2] = fmaf(a4.z, b4.z, acc[2][2]); acc[2][3] = fmaf(a4.z, b4.w, acc[2][3]);
      acc[3][0] = fmaf(a4.w, b4.x, acc[3][0]); acc[3][1] = fmaf(a4.w, b4.y, acc[3][1]);
      acc[3][2] = fmaf(a4.w, b4.z, acc[3][2]); acc[3][3] = fmaf(a4.w, b4.w, acc[3][3]);
    }
  }

  float4 b4 = *(const float4*)(bias + n0 + tx * 4);
#pragma unroll
  for (int i = 0; i < 4; ++i) {
    float4 o;
    o.x = acc[i][0] + b4.x; o.y = acc[i][1] + b4.y;
    o.z = acc[i][2] + b4.z; o.w = acc[i][3] + b4.w;
    *(float4*)(C + (size_t)(m0 + ty * 4 + i) * ldc + n0 + tx * 4) = o;
  }
}

// ---------------------------------------------------------------------------
// Persistent recurrence: tagged dataflow (no device barrier) + VGPR-resident
// weights (pinned pre-loop, 512-reg budget) + per-block LDS h staging +
// raw LDS-only barrier.
//
// h element layout: chunk j (=wave slot) covers h[256j .. 256j+255]; lane l
// owns elements 256j + 4l + 0..3 (contiguous per lane -> poll loads are 4
// consecutive u64/lane, deposit is one ds_write_b128, weights load coalesced).
//
// Step t per wave:
//   B) issue pre[t+1] prefetch (stays in flight across the raw barrier)
//   C) poll my chunk of slot t&1 for tag t (4 consecutive tagged u64/lane);
//      deposit one float4 into lh[t&1]
//   D) s_waitcnt lgkmcnt(0); s_barrier   (vmem NOT drained)
//   E) 3 ds_read_b128 (other chunks) + own chunk from regs, 64 FMAs vs
//      pinned weights, 7-stage reduce, activations, lane 0 publishes unit u
//      with tag t+1 (fire-and-forget).
// Skew safety: every block consumes the FULL h each step -> tag t+2 store
// implies all blocks passed poll t+1 -> depth-2 slots never skip a tag.
// ---------------------------------------------------------------------------
__global__ __launch_bounds__(TPB)
__attribute__((amdgpu_waves_per_eu(1, 1)))
void lstm_rec(
    const float* __restrict__ Ww,                 // [4096, 2048]
    const float* __restrict__ pre,                // [T, 4096]
    unsigned long long* __restrict__ hbuf,        // [2][1024] tagged
    float* __restrict__ hall)                     // [T, 1024]
{
  __shared__ float lh[2][HID];      // 8 KB: staged h, double-buffered

  const int tid = threadIdx.x;
  const int lane = tid & 63;
  const int wslot = tid >> 6;                 // 0..3 = unit-in-block, chunk id
  const int u = blockIdx.x * UPB + wslot;     // this wave's hidden unit

  // Per-lane gate identity (replicated x16 across the wave)
  const int g = lane & 3;            // 0:i 1:f 2:g 3:o
  const size_t preoff = (size_t)g * HID + u;

  // One-time weight load, coalesced: row r_g = g*HID+u (h-part), chunk j,
  // elements 4*lane..4*lane+3. 16 f32x4 = 64 VGPRs.
  f32x4 W00, W01, W02, W03, W10, W11, W12, W13,
        W20, W21, W22, W23, W30, W31, W32, W33;
  {
    const float* base = Ww + IN_DIM + 4 * lane;
#define LOADW(gg, jj) (*(const f32x4*)(base + (size_t)((gg) * HID + u) * (IN_DIM + HID) + (jj) * 256))
    W00 = LOADW(0, 0); W01 = LOADW(0, 1); W02 = LOADW(0, 2); W03 = LOADW(0, 3);
    W10 = LOADW(1, 0); W11 = LOADW(1, 1); W12 = LOADW(1, 2); W13 = LOADW(1, 3);
    W20 = LOADW(2, 0); W21 = LOADW(2, 1); W22 = LOADW(2, 2); W23 = LOADW(2, 3);
    W30 = LOADW(3, 0); W31 = LOADW(3, 1); W32 = LOADW(3, 2); W33 = LOADW(3, 3);
#undef LOADW
  }
  // Opaque pin OUTSIDE the loop: asm outputs cannot be rematerialized by
  // reloading. With the 512-reg budget there is no spill motive either.
  asm volatile("" : "+v"(W00), "+v"(W01), "+v"(W02), "+v"(W03),
                    "+v"(W10), "+v"(W11), "+v"(W12), "+v"(W13),
                    "+v"(W20), "+v"(W21), "+v"(W22), "+v"(W23),
                    "+v"(W30), "+v"(W31), "+v"(W32), "+v"(W33));

  float c = 0.0f;
  float pv = pre[preoff];            // pre-gate for step 0 (pipelined)

  for (int t = 0; t < T_STEPS; ++t) {
    // B) next step's pre load -- full-step latency cover (never drained)
    const int tn = (t + 1 < T_STEPS) ? (t + 1) : t;
    const float pv_next = pre[(size_t)tn * G4 + preoff];

    // C) Poll my chunk of h_{t-1}: 4 consecutive tagged u64 loads/lane
    const unsigned long long* hs =
        hbuf + (size_t)(t & 1) * HID + wslot * 256 + 4 * lane;
    const unsigned want = (unsigned)t;
    unsigned long long p0, p1, p2, p3;
    for (;;) {
      p0 = __hip_atomic_load(hs + 0, __ATOMIC_RELAXED, __HIP_MEMORY_SCOPE_AGENT);
      p1 = __hip_atomic_load(hs + 1, __ATOMIC_RELAXED, __HIP_MEMORY_SCOPE_AGENT);
      p2 = __hip_atomic_load(hs + 2, __ATOMIC_RELAXED, __HIP_MEMORY_SCOPE_AGENT);
      p3 = __hip_atomic_load(hs + 3, __ATOMIC_RELAXED, __HIP_MEMORY_SCOPE_AGENT);
      bool ok = ((unsigned)p0 == want) & ((unsigned)p1 == want) &
                ((unsigned)p2 == want) & ((unsigned)p3 == want);
      if (__all((int)ok)) break;
    }
    f32x4 own;
    own.x = __uint_as_float((unsigned)(p0 >> 32));
    own.y = __uint_as_float((unsigned)(p1 >> 32));
    own.z = __uint_as_float((unsigned)(p2 >> 32));
    own.w = __uint_as_float((unsigned)(p3 >> 32));
    *(f32x4*)&lh[t & 1][wslot * 256 + 4 * lane] = own;   // one ds_write_b128

    // D) raw barrier: drain LDS ops only; global loads/stores stay in flight
    asm volatile("s_waitcnt lgkmcnt(0)\n\ts_barrier" ::: "memory");

    // E) other 3 chunks from LDS (3 x ds_read_b128), own chunk from regs
    const f32x4* lhp = (const f32x4*)&lh[t & 1][0];
    f32x4 hv0 = (wslot == 0) ? own : lhp[0 * 64 + lane];
    f32x4 hv1 = (wslot == 1) ? own : lhp[1 * 64 + lane];
    f32x4 hv2 = (wslot == 2) ? own : lhp[2 * 64 + lane];
    f32x4 hv3 = (wslot == 3) ? own : lhp[3 * 64 + lane];

    // 4 gate-row dots vs pinned weights (64 FMA/lane)
    float a0, a1, a2, a3;
    {
      float a;
      a = 0.0f;
      a = fmaf(W00.x, hv0.x, a); a = fmaf(W00.y, hv0.y, a); a = fmaf(W00.z, hv0.z, a); a = fmaf(W00.w, hv0.w, a);
      a = fmaf(W01.x, hv1.x, a); a = fmaf(W01.y, hv1.y, a); a = fmaf(W01.z, hv1.z, a); a = fmaf(W01.w, hv1.w, a);
      a = fmaf(W02.x, hv2.x, a); a = fmaf(W02.y, hv2.y, a); a = fmaf(W02.z, hv2.z, a); a = fmaf(W02.w, hv2.w, a);
      a = fmaf(W03.x, hv3.x, a); a = fmaf(W03.y, hv3.y, a); a = fmaf(W03.z, hv3.z, a); a = fmaf(W03.w, hv3.w, a);
      a0 = a;
      a = 0.0f;
      a = fmaf(W10.x, hv0.x, a); a = fmaf(W10.y, hv0.y, a); a = fmaf(W10.z, hv0.z, a); a = fmaf(W10.w, hv0.w, a);
      a = fmaf(W11.x, hv1.x, a); a = fmaf(W11.y, hv1.y, a); a = fmaf(W11.z, hv1.z, a); a = fmaf(W11.w, hv1.w, a);
      a = fmaf(W12.x, hv2.x, a); a = fmaf(W12.y, hv2.y, a); a = fmaf(W12.z, hv2.z, a); a = fmaf(W12.w, hv2.w, a);
      a = fmaf(W13.x, hv3.x, a); a = fmaf(W13.y, hv3.y, a); a = fmaf(W13.z, hv3.z, a); a = fmaf(W13.w, hv3.w, a);
      a1 = a;
      a = 0.0f;
      a = fmaf(W20.x, hv0.x, a); a = fmaf(W20.y, hv0.y, a); a = fmaf(W20.z, hv0.z, a); a = fmaf(W20.w, hv0.w, a);
      a = fmaf(W21.x, hv1.x, a); a = fmaf(W21.y, hv1.y, a); a = fmaf(W21.z, hv1.z, a); a = fmaf(W21.w, hv1.w, a);
      a = fmaf(W22.x, hv2.x, a); a = fmaf(W22.y, hv2.y, a); a = fmaf(W22.z, hv2.z, a); a = fmaf(W22.w, hv2.w, a);
      a = fmaf(W23.x, hv3.x, a); a = fmaf(W23.y, hv3.y, a); a = fmaf(W23.z, hv3.z, a); a = fmaf(W23.w, hv3.w, a);
      a2 = a;
      a = 0.0f;
      a = fmaf(W30.x, hv0.x, a); a = fmaf(W30.y, hv0.y, a); a = fmaf(W30.z, hv0.z, a); a = fmaf(W30.w, hv0.w, a);
      a = fmaf(W31.x, hv1.x, a); a = fmaf(W31.y, hv1.y, a); a = fmaf(W31.z, hv1.z, a); a = fmaf(W31.w, hv1.w, a);
      a = fmaf(W32.x, hv2.x, a); a = fmaf(W32.y, hv2.y, a); a = fmaf(W32.z, hv2.z, a); a = fmaf(W32.w, hv2.w, a);
      a = fmaf(W33.x, hv3.x, a); a = fmaf(W33.y, hv3.y, a); a = fmaf(W33.z, hv3.z, a); a = fmaf(W33.w, hv3.w, a);
      a3 = a;
    }

    // Halving reduce: 3 shuffles land gate (lane&3) in lane; 4 butterflies
    float r0 = halvestep(a0, a1, 1, lane);
    float r1 = halvestep(a2, a3, 1, lane);
    float s  = halvestep(r0, r1, 2, lane);
    s += __shfl_xor(s, 4); s += __shfl_xor(s, 8);
    s += __shfl_xor(s, 16); s += __shfl_xor(s, 32);
    // lane l holds the full pre-activation sum for gate l&3

    const float gv = s + pv;
    // sigmoid for i,f,o; tanh for g via 2*sig(2x)-1
    const bool isg = (g == 2);
    const float sg = sigf(isg ? 2.0f * gv : gv);
    const float act = isg ? fmaf(2.0f, sg, -1.0f) : sg;

    // gather my quad's four gate activations
    const int base = lane & ~3;
    const float si = __shfl(act, base);
    const float sf = __shfl(act, base | 1);
    const float tg = __shfl(act, base | 2);
    const float so = __shfl(act, base | 3);

    c = fmaf(sf, c, si * tg);
    const float s2 = sigf(2.0f * c);
    const float h = so * fmaf(2.0f, s2, -1.0f);   // so * tanh(c)

    if (lane == 0) {
      unsigned long long pk =
          ((unsigned long long)__float_as_uint(h) << 32) | (unsigned)(t + 1);
      __hip_atomic_store(hbuf + (size_t)((t + 1) & 1) * HID + u, pk,
                         __ATOMIC_RELAXED, __HIP_MEMORY_SCOPE_AGENT);
      hall[(size_t)t * HID + u] = h;
    }

    pv = pv_next;
  }
}

// ---------------------------------------------------------------------------
// Workspace layout (bytes):
//   [0, 16K)              : hbuf[2][1024] tagged u64  (memset 0: tag0/h=0)
//   [16K, 16K+33.5MB)     : hall[T][1024]
//   [16K+33.5MB, +134MB)  : pre[T][4096]
// ---------------------------------------------------------------------------
extern "C" void kernel_launch(void* const* d_in, const int* in_sizes, int n_in,
                              void* d_out, int out_size, void* d_ws, size_t ws_size,
                              hipStream_t stream) {
  (void)in_sizes; (void)n_in; (void)out_size; (void)ws_size;

  const float* x     = (const float*)d_in[0];  // [T,1,IN]
  const float* W_w   = (const float*)d_in[1];  // [4096, 2048]
  const float* W_b   = (const float*)d_in[2];  // [4096]
  const float* out_w = (const float*)d_in[3];  // [1024, 1024]
  const float* out_b = (const float*)d_in[4];  // [1024]
  float* out = (float*)d_out;                  // [T,1,1024]

  char* ws = (char*)d_ws;
  unsigned long long* hbuf = (unsigned long long*)ws;
  float* hall = (float*)(ws + 16384);
  float* pre  = (float*)(ws + 16384 + (size_t)T_STEPS * HID * 4);

  hipMemsetAsync(ws, 0, 16384, stream);

  // pre = x @ Wx^T + W_b   (Wx = W_w[:, :1024], row stride 2048)
  gemm_nt<<<dim3(G4 / 64, T_STEPS / 64), 256, 0, stream>>>(
      x, IN_DIM, W_w, IN_DIM + HID, W_b, pre, G4, IN_DIM);

  // sequential recurrence: 256 blocks (1/CU), VGPR-resident weights
  lstm_rec<<<NBLK, TPB, 0, stream>>>(W_w, pre, hbuf, hall);

  // y = hall @ out_w^T + out_b
  gemm_nt<<<dim3(OUT_DIM / 64, T_STEPS / 64), 256, 0, stream>>>(
      hall, HID, out_w, OUT_DIM, out_b, out, OUT_DIM, HID);
}